// Round 7
// baseline (1035.027 us; speedup 1.0000x reference)
//
#include <hip/hip_runtime.h>
#include <math.h>

#define BT 8192      // B*T
#define NDIM 512     // INPUT_DIM
#define NFREQ 257
#define DDIM 128     // VQ_DIM
#define NEMBED 8192
#define NQ 8         // codebook slices (occupancy: 1024 blocks = 4/CU)
#define ROWS 32768   // BT*4 splits

typedef _Float16 half8 __attribute__((ext_vector_type(8)));
typedef _Float16 half2v __attribute__((ext_vector_type(2)));
typedef float f32x4 __attribute__((ext_vector_type(4)));

#define SCALE_DN 2.44140625e-4f   // 2^-12

// ------- W^T split (K-table fused): per block, rebuild K_s then window-conv ------------
// Wth/Wtl[c][k] = f16split(256 * sum_p proj[p][c&127] K_s[(p-k)&511])
__global__ __launch_bounds__(128) void build_W_split(const float* __restrict__ proj,
                                                     const int* __restrict__ rm,
                                                     _Float16* __restrict__ Wth,
                                                     _Float16* __restrict__ Wtl) {
    int nt = blockIdx.x, s = blockIdx.y, d = threadIdx.x;
    int n0 = nt * 8;
    __shared__ float ctab[512];
    __shared__ float Ks[512];
    __shared__ int rms[NFREQ];
    for (int i = d; i < 512; i += 128) ctab[i] = cospif((float)i * (1.0f / 256.0f));
    for (int i = d; i < NFREQ; i += 128) rms[i] = rm[i];
    __syncthreads();
    // K_s[delta] = (1/512) * sum_{f: rm[f]==s} w_f * cos(2*pi*f*delta/512), f ascending
    for (int base = d; base < 512; base += 128) {
        float acc = 0.0f;
        for (int f = 0; f < NFREQ; ++f) {
            float w = (f == 0 || f == 256) ? 1.0f : 2.0f;
            float c = w * ctab[(f * base) & 511];
            acc += (rms[f] == s) ? c : 0.0f;
        }
        Ks[base] = acc * (1.0f / 512.0f);
    }
    __syncthreads();
    float acc[8] = {};
    for (int p16 = 0; p16 < 512; p16 += 16) {
        float wv[23];
#pragma unroll
        for (int j2 = 0; j2 < 23; ++j2) wv[j2] = Ks[(p16 - n0 + j2 - 7) & 511];
#pragma unroll
        for (int j = 0; j < 16; ++j) {
            float xp = proj[(p16 + j) * DDIM + d];
#pragma unroll
            for (int i = 0; i < 8; ++i)
                acc[i] = fmaf(xp, wv[7 + j - i], acc[i]);
        }
    }
    size_t cbase = (size_t)(s * DDIM + d) * 512 + n0;
#pragma unroll
    for (int i = 0; i < 8; ++i) {
        float f = acc[i] * 256.0f;          // pre-scale: dodge f16 denormals (norm cancels)
        _Float16 h = (_Float16)f;
        Wth[cbase + i] = h;
        Wtl[cbase + i] = (_Float16)((f - (float)h) * 4096.0f);
    }
}

// ---- codebook: normalize + f16 hi/lo split, written in MFMA B-FRAGMENT order ----------
// image (halfs): tile*2048 + kt*512 + lg*128 + cr*8 + j, where code=tile*16+cr,
// k = kt*32 + lg*8 + j. Sim lane l then reads contiguous 16B at tile*2048+kt*512+l*8.
__global__ __launch_bounds__(256) void cbsplit_kernel(const float* __restrict__ cb,
                                                      _Float16* __restrict__ chi,
                                                      _Float16* __restrict__ clo) {
    int code = blockIdx.x * 4 + (threadIdx.x >> 6);
    int l = threadIdx.x & 63;                 // handles k = 2l, 2l+1
    float2 v = ((const float2*)(cb + (size_t)code * DDIM))[l];
    float ss = fmaf(v.x, v.x, v.y * v.y);
#pragma unroll
    for (int m = 32; m; m >>= 1) ss += __shfl_xor(ss, m);
    float r = 1.0f / sqrtf(ss);
    float a = v.x * r, b = v.y * r;
    _Float16 ha = (_Float16)a, hb = (_Float16)b;
    half2v hv = {ha, hb};
    half2v lv = {(_Float16)((a - (float)ha) * 4096.0f), (_Float16)((b - (float)hb) * 4096.0f)};
    int cr = code & 15, tile = code >> 4;
    int kt = l >> 4, lg = (l >> 2) & 3, j = 2 * (l & 3);
    size_t addr = (size_t)tile * 2048 + kt * 512 + lg * 128 + cr * 8 + j;
    *(half2v*)(chi + addr) = hv;
    *(half2v*)(clo + addr) = lv;
}

// ---------------- fused feat: feat = x @ W (f16x3 MFMA), row-normalize, split hi/lo -----
__global__ __launch_bounds__(256) void fused_feat(const float* __restrict__ x,
                                                  const _Float16* __restrict__ Wth,
                                                  const _Float16* __restrict__ Wtl,
                                                  _Float16* __restrict__ fhi,
                                                  _Float16* __restrict__ flo) {
    __shared__ __align__(16) char smem[59392];
    float* xs = (float*)smem;                       // [2][64][36] f32
    _Float16* Wh = (_Float16*)(smem + 18432);       // [2][128][40] f16
    _Float16* Wl = (_Float16*)(smem + 38912);       // [2][128][40] f16

    int t = threadIdx.x;
    int w = t >> 6, lr = t & 15, lg = (t >> 4) & 3;
    int row0 = blockIdx.x * 64;
    int sIdx = blockIdx.y;

    int xr_r = t >> 2, xr_c = (t & 3) * 8;
    int wcol = t >> 1, wh_h = t & 1;
    const float* xsrc = x + (size_t)(row0 + xr_r) * NDIM + xr_c;
    const _Float16* whsrc = Wth + (size_t)(sIdx * 128 + wcol) * 512 + wh_h * 16;
    const _Float16* wlsrc = Wtl + (size_t)(sIdx * 128 + wcol) * 512 + wh_h * 16;

    f32x4 c0[8], c1[8];
#pragma unroll
    for (int i = 0; i < 8; ++i) { c0[i] = (f32x4){0.f,0.f,0.f,0.f}; c1[i] = c0[i]; }

    {
        float4 a0 = *(const float4*)(xsrc);
        float4 a1 = *(const float4*)(xsrc + 4);
        *(float4*)&xs[xr_r * 36 + xr_c] = a0;
        *(float4*)&xs[xr_r * 36 + xr_c + 4] = a1;
        half8 h0 = *(const half8*)(whsrc);
        half8 h1 = *(const half8*)(whsrc + 8);
        half8 l0 = *(const half8*)(wlsrc);
        half8 l1 = *(const half8*)(wlsrc + 8);
        *(half8*)&Wh[wcol * 40 + wh_h * 16] = h0;
        *(half8*)&Wh[wcol * 40 + wh_h * 16 + 8] = h1;
        *(half8*)&Wl[wcol * 40 + wh_h * 16] = l0;
        *(half8*)&Wl[wcol * 40 + wh_h * 16 + 8] = l1;
    }

    for (int it = 0; it < 16; ++it) {
        __syncthreads();
        int buf = it & 1;
        float4 nx0, nx1; half8 nh0, nh1, nl0, nl1;
        bool have = (it + 1) < 16;
        if (have) {
            int k0 = (it + 1) * 32;
            nx0 = *(const float4*)(xsrc + k0);
            nx1 = *(const float4*)(xsrc + k0 + 4);
            nh0 = *(const half8*)(whsrc + k0);
            nh1 = *(const half8*)(whsrc + k0 + 8);
            nl0 = *(const half8*)(wlsrc + k0);
            nl1 = *(const half8*)(wlsrc + k0 + 8);
        }
        const float* xb = xs + buf * 2304;
        float4 f0 = *(const float4*)&xb[(w * 16 + lr) * 36 + lg * 8];
        float4 f1 = *(const float4*)&xb[(w * 16 + lr) * 36 + lg * 8 + 4];
        float fv[8] = {f0.x, f0.y, f0.z, f0.w, f1.x, f1.y, f1.z, f1.w};
        half8 ah, al;
#pragma unroll
        for (int j = 0; j < 8; ++j) {
            _Float16 h = (_Float16)fv[j];
            ah[j] = h;
            al[j] = (_Float16)((fv[j] - (float)h) * 4096.0f);
        }
        const _Float16* whb = Wh + buf * 5120;
        const _Float16* wlb = Wl + buf * 5120;
#pragma unroll
        for (int set = 0; set < 8; ++set) {
            int bcol = set * 16 + lr;
            half8 bh = *(const half8*)&whb[bcol * 40 + lg * 8];
            half8 bl = *(const half8*)&wlb[bcol * 40 + lg * 8];
            c0[set] = __builtin_amdgcn_mfma_f32_16x16x32_f16(ah, bh, c0[set], 0, 0, 0);
            c1[set] = __builtin_amdgcn_mfma_f32_16x16x32_f16(ah, bl, c1[set], 0, 0, 0);
            c1[set] = __builtin_amdgcn_mfma_f32_16x16x32_f16(al, bh, c1[set], 0, 0, 0);
        }
        __syncthreads();
        if (have) {
            *(float4*)&xs[(buf ^ 1) * 2304 + xr_r * 36 + xr_c] = nx0;
            *(float4*)&xs[(buf ^ 1) * 2304 + xr_r * 36 + xr_c + 4] = nx1;
            _Float16* dh = Wh + (buf ^ 1) * 5120 + wcol * 40 + wh_h * 16;
            _Float16* dl = Wl + (buf ^ 1) * 5120 + wcol * 40 + wh_h * 16;
            *(half8*)(dh) = nh0; *(half8*)(dh + 8) = nh1;
            *(half8*)(dl) = nl0; *(half8*)(dl + 8) = nl1;
        }
    }
    __syncthreads();

    float* few = (float*)smem + w * 2112;           // [16][132]
    float ss[4] = {0.f, 0.f, 0.f, 0.f};
    float vv[8][4];
#pragma unroll
    for (int set = 0; set < 8; ++set)
#pragma unroll
        for (int r = 0; r < 4; ++r) {
            float v = fmaf(c1[set][r], SCALE_DN, c0[set][r]);
            vv[set][r] = v;
            ss[r] = fmaf(v, v, ss[r]);
        }
#pragma unroll
    for (int r = 0; r < 4; ++r) {
#pragma unroll
        for (int m = 1; m < 16; m <<= 1) ss[r] += __shfl_xor(ss[r], m);
    }
    float rn[4];
#pragma unroll
    for (int r = 0; r < 4; ++r) rn[r] = rsqrtf(ss[r]);
#pragma unroll
    for (int set = 0; set < 8; ++set)
#pragma unroll
        for (int r = 0; r < 4; ++r)
            few[(4 * lg + r) * 132 + set * 16 + lr] = vv[set][r] * rn[r];
    __syncthreads();
    int l = t & 63;
    int rr = l >> 2, q = l & 3;
    size_t btg = (size_t)(row0 + w * 16 + rr);
    size_t dst = (btg * 4 + sIdx) * DDIM + q * 32;
#pragma unroll
    for (int g = 0; g < 4; ++g) {
        half8 oh, ol;
#pragma unroll
        for (int j = 0; j < 8; ++j) {
            float f = few[rr * 132 + q * 32 + g * 8 + j];
            _Float16 h = (_Float16)f;
            oh[j] = h;
            ol[j] = (_Float16)((f - (float)h) * 4096.0f);
        }
        *(half8*)(fhi + dst + g * 8) = oh;
        *(half8*)(flo + dst + g * 8) = ol;
    }
}

// ---------------- sim + argmax partial: 256 feat rows x 1024-code slice ----------------
// grid (128 row-tiles, 8 slices) = 1024 blocks = 4/CU = 4 waves/SIMD. B fragments
// loaded global->reg from the fragment-ordered codebook image. No LDS in main loop.
__global__ __launch_bounds__(256, 4) void sim_argmax_part(const _Float16* __restrict__ fhi,
                                                          const _Float16* __restrict__ flo,
                                                          const _Float16* __restrict__ chi,
                                                          const _Float16* __restrict__ clo,
                                                          float* __restrict__ pv,
                                                          int* __restrict__ pi) {
    __shared__ float redv[256][17];
    __shared__ int   redi[256][17];

    int t = threadIdx.x;
    int w = t >> 6, l = t & 63, lr = t & 15, lg = (t >> 4) & 3;
    int row0 = blockIdx.x * 256;
    int q = blockIdx.y;

    // A fragments (4 sets x 4 kt), resident whole kernel: 128 VGPR
    half8 ahi[4][4], alo[4][4];
#pragma unroll
    for (int s = 0; s < 4; ++s)
#pragma unroll
        for (int kt = 0; kt < 4; ++kt) {
            size_t off = (size_t)(row0 + w * 64 + s * 16 + lr) * DDIM + kt * 32 + lg * 8;
            ahi[s][kt] = *(const half8*)(fhi + off);
            alo[s][kt] = *(const half8*)(flo + off);
        }

    // fragment-order image: half8 index = tile*256 + kt*64 + lane
    const half8* cf = (const half8*)chi;
    const half8* cv = (const half8*)clo;
    size_t base = (size_t)(q * (NEMBED / NQ / 16)) * 256 + l;   // slice tile base + lane

    half8 bh[4], bl[4];
#pragma unroll
    for (int kt = 0; kt < 4; ++kt) {
        bh[kt] = cf[base + kt * 64];
        bl[kt] = cv[base + kt * 64];
    }

    float best[4][4];
    int btile[4][4];
#pragma unroll
    for (int s = 0; s < 4; ++s)
#pragma unroll
        for (int r = 0; r < 4; ++r) { best[s][r] = -1e30f; btile[s][r] = 0; }

    const int NT = NEMBED / (16 * NQ);   // 64 tiles per slice
    for (int it = 0; it < NT; ++it) {
        f32x4 a0[4], a1[4];
#pragma unroll
        for (int s = 0; s < 4; ++s) { a0[s] = (f32x4){0.f,0.f,0.f,0.f}; a1[s] = a0[s]; }
        size_t nb = base + (size_t)(it + 1) * 256;
        bool have = (it + 1) < NT;
#pragma unroll
        for (int kt = 0; kt < 4; ++kt) {
#pragma unroll
            for (int s = 0; s < 4; ++s) {
                a0[s] = __builtin_amdgcn_mfma_f32_16x16x32_f16(ahi[s][kt], bh[kt], a0[s], 0, 0, 0);
                a1[s] = __builtin_amdgcn_mfma_f32_16x16x32_f16(ahi[s][kt], bl[kt], a1[s], 0, 0, 0);
                a1[s] = __builtin_amdgcn_mfma_f32_16x16x32_f16(alo[s][kt], bh[kt], a1[s], 0, 0, 0);
            }
            if (have) {   // WAR-safe: MFMAs above already read bh/bl at issue
                bh[kt] = cf[nb + kt * 64];
                bl[kt] = cv[nb + kt * 64];
            }
        }
#pragma unroll
        for (int s = 0; s < 4; ++s)
#pragma unroll
            for (int r = 0; r < 4; ++r) {
                float v = fmaf(a1[s][r], SCALE_DN, a0[s][r]);
                if (v > best[s][r]) { best[s][r] = v; btile[s][r] = it; }
            }
    }

#pragma unroll
    for (int s = 0; s < 4; ++s)
#pragma unroll
        for (int r = 0; r < 4; ++r) {
            int row = w * 64 + s * 16 + 4 * lg + r;
            redv[row][lr] = best[s][r];
            redi[row][lr] = q * (NEMBED / NQ) + btile[s][r] * 16 + lr;
        }
    __syncthreads();
    {
        float bv = redv[t][0]; int bi = redi[t][0];
#pragma unroll
        for (int c = 1; c < 16; ++c) {
            float v = redv[t][c]; int ii = redi[t][c];
            if (v > bv || (v == bv && ii < bi)) { bv = v; bi = ii; }
        }
        pv[(size_t)q * ROWS + row0 + t] = bv;
        pi[(size_t)q * ROWS + row0 + t] = bi;
    }
}

// ---------------- merge NQ slice-candidates per row -------------------------------------
__global__ __launch_bounds__(256) void merge_argmax(const float* __restrict__ pv,
                                                    const int* __restrict__ pi,
                                                    int* __restrict__ out) {
    int row = blockIdx.x * 256 + threadIdx.x;
    float bv = pv[row]; int bi = pi[row];
#pragma unroll
    for (int q = 1; q < NQ; ++q) {
        float v = pv[(size_t)q * ROWS + row];
        if (v > bv) { bv = v; bi = pi[(size_t)q * ROWS + row]; }   // ties -> lower q wins
    }
    out[row] = bi;
}

extern "C" void kernel_launch(void* const* d_in, const int* in_sizes, int n_in,
                              void* d_out, int out_size, void* d_ws, size_t ws_size,
                              hipStream_t stream) {
    const float* x    = (const float*)d_in[0];   // [32,256,512]
    const float* proj = (const float*)d_in[1];   // [512,128]
    const float* cb   = (const float*)d_in[2];   // [1,8192,128]
    const int*   rm   = (const int*)d_in[3];     // [257]
    int* out = (int*)d_out;                      // [32,256,4,1] int32

    char* wsb = (char*)d_ws;
    _Float16* Wth  = (_Float16*)(wsb + 0);           // 512 KB
    _Float16* Wtl  = (_Float16*)(wsb + 524288);      // 512 KB
    _Float16* chi  = (_Float16*)(wsb + 1048576);     // 2 MB (B-fragment order)
    _Float16* clo  = (_Float16*)(wsb + 3145728);     // 2 MB
    _Float16* fhi  = (_Float16*)(wsb + 5242880);     // 8 MB
    _Float16* flo  = (_Float16*)(wsb + 13631488);    // 8 MB
    float*    pv   = (float*)(wsb + 22020096);       // 1 MB (8 x 32768)
    int*      pi   = (int*)(wsb + 23068672);         // 1 MB (end ~24 MB)

    build_W_split<<<dim3(64, 4), 128, 0, stream>>>(proj, rm, Wth, Wtl);
    cbsplit_kernel<<<NEMBED / 4, 256, 0, stream>>>(cb, chi, clo);
    fused_feat<<<dim3(128, 4), 256, 0, stream>>>(x, Wth, Wtl, fhi, flo);
    sim_argmax_part<<<dim3(ROWS / 256, NQ), 256, 0, stream>>>(fhi, flo, chi, clo, pv, pi);
    merge_argmax<<<ROWS / 256, 256, 0, stream>>>(pv, pi, out);
}

// Round 8
// 287.486 us; speedup vs baseline: 3.6003x; 3.6003x over previous
//
#include <hip/hip_runtime.h>
#include <math.h>

#define BT 8192      // B*T
#define NDIM 512     // INPUT_DIM
#define NFREQ 257
#define DDIM 128     // VQ_DIM
#define NEMBED 8192
#define NQ 4         // codebook slices
#define ROWS 32768   // BT*4 splits

typedef _Float16 half8 __attribute__((ext_vector_type(8)));
typedef float f32x4 __attribute__((ext_vector_type(4)));

#define SCALE_DN 2.44140625e-4f   // 2^-12

// ---------------- prep kernel: blocks [0,512) = codebook split; [512,640) = W build ----
// cb part: per 16-code tile, stage f32 in LDS, normalize, f16 hi/lo split, write the
// B-fragment-ordered image with fully-coalesced half8 stores.
// W part: rebuild K_s from cos LUT, window-conv against proj, write Wth/Wtl transposed.
__global__ __launch_bounds__(256) void prep_kernel(const float* __restrict__ cb,
                                                   const float* __restrict__ proj,
                                                   const int* __restrict__ rm,
                                                   _Float16* __restrict__ chi,
                                                   _Float16* __restrict__ clo,
                                                   _Float16* __restrict__ Wth,
                                                   _Float16* __restrict__ Wtl) {
    int t = threadIdx.x;
    if (blockIdx.x < 512) {
        // ---- codebook split ----
        __shared__ float tile[16][132];
        __shared__ float rns[16];
        int tileIdx = blockIdx.x;
        int row = t >> 4, seg = t & 15;
        const float* src = cb + ((size_t)tileIdx * 16 + row) * DDIM + seg * 8;
        float4 v0 = *(const float4*)src;
        float4 v1 = *(const float4*)(src + 4);
        *(float4*)&tile[row][seg * 8] = v0;
        *(float4*)&tile[row][seg * 8 + 4] = v1;
        float ss = v0.x * v0.x;
        ss = fmaf(v0.y, v0.y, ss); ss = fmaf(v0.z, v0.z, ss); ss = fmaf(v0.w, v0.w, ss);
        ss = fmaf(v1.x, v1.x, ss); ss = fmaf(v1.y, v1.y, ss);
        ss = fmaf(v1.z, v1.z, ss); ss = fmaf(v1.w, v1.w, ss);
#pragma unroll
        for (int m = 1; m < 16; m <<= 1) ss += __shfl_xor(ss, m);
        if (seg == 0) rns[row] = 1.0f / sqrtf(ss);
        __syncthreads();
        int cr = t & 15, lgq = (t >> 4) & 3, kt = t >> 6;
        int k0 = kt * 32 + lgq * 8;
        float rn = rns[cr];
        half8 oh, ol;
#pragma unroll
        for (int j = 0; j < 8; ++j) {
            float f = tile[cr][k0 + j] * rn;
            _Float16 h = (_Float16)f;
            oh[j] = h;
            ol[j] = (_Float16)((f - (float)h) * 4096.0f);
        }
        size_t dst = (size_t)tileIdx * 2048 + t * 8;
        *(half8*)(chi + dst) = oh;
        *(half8*)(clo + dst) = ol;
    } else {
        // ---- W^T build + f16 split ----
        __shared__ float ctab[512];
        __shared__ float Ks[512];
        __shared__ int rms[NFREQ];
        int bxp = blockIdx.x - 512;          // [0,128)
        int s = bxp & 3, ntp = bxp >> 2;     // s split, 16-k group
        int d = t & 127;
        int n0 = ntp * 16 + (t >> 7) * 8;
        for (int i = t; i < 512; i += 256) ctab[i] = cospif((float)i * (1.0f / 256.0f));
        for (int i = t; i < NFREQ; i += 256) rms[i] = rm[i];
        __syncthreads();
        for (int base = t; base < 512; base += 256) {
            float acc = 0.0f;
            for (int f = 0; f < NFREQ; ++f) {
                float w = (f == 0 || f == 256) ? 1.0f : 2.0f;
                float c = w * ctab[(f * base) & 511];
                acc += (rms[f] == s) ? c : 0.0f;
            }
            Ks[base] = acc * (1.0f / 512.0f);
        }
        __syncthreads();
        float acc[8] = {};
        for (int p16 = 0; p16 < 512; p16 += 16) {
            float wv[23];
#pragma unroll
            for (int j2 = 0; j2 < 23; ++j2) wv[j2] = Ks[(p16 - n0 + j2 - 7) & 511];
#pragma unroll
            for (int j = 0; j < 16; ++j) {
                float xp = proj[(p16 + j) * DDIM + d];
#pragma unroll
                for (int i = 0; i < 8; ++i)
                    acc[i] = fmaf(xp, wv[7 + j - i], acc[i]);
            }
        }
        size_t cbase = (size_t)(s * DDIM + d) * 512 + n0;
#pragma unroll
        for (int i = 0; i < 8; ++i) {
            float f = acc[i] * 256.0f;      // pre-scale: dodge f16 denormals (norm cancels)
            _Float16 h = (_Float16)f;
            Wth[cbase + i] = h;
            Wtl[cbase + i] = (_Float16)((f - (float)h) * 4096.0f);
        }
    }
}

// ---------------- fused feat: feat = x @ W (f16x3 MFMA), row-normalize, split hi/lo -----
__global__ __launch_bounds__(256) void fused_feat(const float* __restrict__ x,
                                                  const _Float16* __restrict__ Wth,
                                                  const _Float16* __restrict__ Wtl,
                                                  _Float16* __restrict__ fhi,
                                                  _Float16* __restrict__ flo) {
    __shared__ __align__(16) char smem[59392];
    float* xs = (float*)smem;                       // [2][64][36] f32
    _Float16* Wh = (_Float16*)(smem + 18432);       // [2][128][40] f16
    _Float16* Wl = (_Float16*)(smem + 38912);       // [2][128][40] f16

    int t = threadIdx.x;
    int w = t >> 6, lr = t & 15, lg = (t >> 4) & 3;
    int row0 = blockIdx.x * 64;
    int sIdx = blockIdx.y;

    int xr_r = t >> 2, xr_c = (t & 3) * 8;
    int wcol = t >> 1, wh_h = t & 1;
    const float* xsrc = x + (size_t)(row0 + xr_r) * NDIM + xr_c;
    const _Float16* whsrc = Wth + (size_t)(sIdx * 128 + wcol) * 512 + wh_h * 16;
    const _Float16* wlsrc = Wtl + (size_t)(sIdx * 128 + wcol) * 512 + wh_h * 16;

    f32x4 c0[8], c1[8];
#pragma unroll
    for (int i = 0; i < 8; ++i) { c0[i] = (f32x4){0.f,0.f,0.f,0.f}; c1[i] = c0[i]; }

    {
        float4 a0 = *(const float4*)(xsrc);
        float4 a1 = *(const float4*)(xsrc + 4);
        *(float4*)&xs[xr_r * 36 + xr_c] = a0;
        *(float4*)&xs[xr_r * 36 + xr_c + 4] = a1;
        half8 h0 = *(const half8*)(whsrc);
        half8 h1 = *(const half8*)(whsrc + 8);
        half8 l0 = *(const half8*)(wlsrc);
        half8 l1 = *(const half8*)(wlsrc + 8);
        *(half8*)&Wh[wcol * 40 + wh_h * 16] = h0;
        *(half8*)&Wh[wcol * 40 + wh_h * 16 + 8] = h1;
        *(half8*)&Wl[wcol * 40 + wh_h * 16] = l0;
        *(half8*)&Wl[wcol * 40 + wh_h * 16 + 8] = l1;
    }

    for (int it = 0; it < 16; ++it) {
        __syncthreads();
        int buf = it & 1;
        float4 nx0, nx1; half8 nh0, nh1, nl0, nl1;
        bool have = (it + 1) < 16;
        if (have) {
            int k0 = (it + 1) * 32;
            nx0 = *(const float4*)(xsrc + k0);
            nx1 = *(const float4*)(xsrc + k0 + 4);
            nh0 = *(const half8*)(whsrc + k0);
            nh1 = *(const half8*)(whsrc + k0 + 8);
            nl0 = *(const half8*)(wlsrc + k0);
            nl1 = *(const half8*)(wlsrc + k0 + 8);
        }
        const float* xb = xs + buf * 2304;
        float4 f0 = *(const float4*)&xb[(w * 16 + lr) * 36 + lg * 8];
        float4 f1 = *(const float4*)&xb[(w * 16 + lr) * 36 + lg * 8 + 4];
        float fv[8] = {f0.x, f0.y, f0.z, f0.w, f1.x, f1.y, f1.z, f1.w};
        half8 ah, al;
#pragma unroll
        for (int j = 0; j < 8; ++j) {
            _Float16 h = (_Float16)fv[j];
            ah[j] = h;
            al[j] = (_Float16)((fv[j] - (float)h) * 4096.0f);
        }
        const _Float16* whb = Wh + buf * 5120;
        const _Float16* wlb = Wl + buf * 5120;
#pragma unroll
        for (int set = 0; set < 8; ++set) {
            int bcol = set * 16 + lr;
            half8 bh = *(const half8*)&whb[bcol * 40 + lg * 8];
            half8 bl = *(const half8*)&wlb[bcol * 40 + lg * 8];
            c0[set] = __builtin_amdgcn_mfma_f32_16x16x32_f16(ah, bh, c0[set], 0, 0, 0);
            c1[set] = __builtin_amdgcn_mfma_f32_16x16x32_f16(ah, bl, c1[set], 0, 0, 0);
            c1[set] = __builtin_amdgcn_mfma_f32_16x16x32_f16(al, bh, c1[set], 0, 0, 0);
        }
        __syncthreads();
        if (have) {
            *(float4*)&xs[(buf ^ 1) * 2304 + xr_r * 36 + xr_c] = nx0;
            *(float4*)&xs[(buf ^ 1) * 2304 + xr_r * 36 + xr_c + 4] = nx1;
            _Float16* dh = Wh + (buf ^ 1) * 5120 + wcol * 40 + wh_h * 16;
            _Float16* dl = Wl + (buf ^ 1) * 5120 + wcol * 40 + wh_h * 16;
            *(half8*)(dh) = nh0; *(half8*)(dh + 8) = nh1;
            *(half8*)(dl) = nl0; *(half8*)(dl + 8) = nl1;
        }
    }
    __syncthreads();

    float* few = (float*)smem + w * 2112;           // [16][132]
    float ss[4] = {0.f, 0.f, 0.f, 0.f};
    float vv[8][4];
#pragma unroll
    for (int set = 0; set < 8; ++set)
#pragma unroll
        for (int r = 0; r < 4; ++r) {
            float v = fmaf(c1[set][r], SCALE_DN, c0[set][r]);
            vv[set][r] = v;
            ss[r] = fmaf(v, v, ss[r]);
        }
#pragma unroll
    for (int r = 0; r < 4; ++r) {
#pragma unroll
        for (int m = 1; m < 16; m <<= 1) ss[r] += __shfl_xor(ss[r], m);
    }
    float rn[4];
#pragma unroll
    for (int r = 0; r < 4; ++r) rn[r] = rsqrtf(ss[r]);
#pragma unroll
    for (int set = 0; set < 8; ++set)
#pragma unroll
        for (int r = 0; r < 4; ++r)
            few[(4 * lg + r) * 132 + set * 16 + lr] = vv[set][r] * rn[r];
    __syncthreads();
    int l = t & 63;
    int rr = l >> 2, q = l & 3;
    size_t btg = (size_t)(row0 + w * 16 + rr);
    size_t dst = (btg * 4 + sIdx) * DDIM + q * 32;
#pragma unroll
    for (int g = 0; g < 4; ++g) {
        half8 oh, ol;
#pragma unroll
        for (int j = 0; j < 8; ++j) {
            float f = few[rr * 132 + q * 32 + g * 8 + j];
            _Float16 h = (_Float16)f;
            oh[j] = h;
            ol[j] = (_Float16)((f - (float)h) * 4096.0f);
        }
        *(half8*)(fhi + dst + g * 8) = oh;
        *(half8*)(flo + dst + g * 8) = ol;
    }
}

// ---------------- sim + argmax partial: 256 feat rows x 2048-code slice -----------------
// grid (128 row-tiles, 4 slices); 4 waves x 64 rows. Pipelined combine: row-set pairs
// {0,1} and {2,3}; pair B of tile it-1 is combined while pair A of tile it runs MFMAs.
// All combine VALU reads completed accumulators -> no MFMA drain bubble.
__global__ __launch_bounds__(256, 2) void sim_argmax_part(const _Float16* __restrict__ fhi,
                                                          const _Float16* __restrict__ flo,
                                                          const _Float16* __restrict__ chi,
                                                          const _Float16* __restrict__ clo,
                                                          float* __restrict__ pv,
                                                          int* __restrict__ pi) {
    __shared__ float redv[256][17];
    __shared__ int   redi[256][17];

    int t = threadIdx.x;
    int w = t >> 6, l = t & 63, lr = t & 15, lg = (t >> 4) & 3;
    int row0 = blockIdx.x * 256;
    int q = blockIdx.y;

    // A fragments (4 sets x 4 kt), resident whole kernel
    half8 ahi[4][4], alo[4][4];
#pragma unroll
    for (int s = 0; s < 4; ++s)
#pragma unroll
        for (int kt = 0; kt < 4; ++kt) {
            size_t off = (size_t)(row0 + w * 64 + s * 16 + lr) * DDIM + kt * 32 + lg * 8;
            ahi[s][kt] = *(const half8*)(fhi + off);
            alo[s][kt] = *(const half8*)(flo + off);
        }

    // fragment-order image: half8 index = tile*256 + kt*64 + lane
    const half8* cf = (const half8*)chi;
    const half8* cv = (const half8*)clo;
    size_t base = (size_t)(q * (NEMBED / NQ / 16)) * 256 + l;

    half8 bh[4], bl[4];
#pragma unroll
    for (int kt = 0; kt < 4; ++kt) {
        bh[kt] = cf[base + kt * 64];
        bl[kt] = cv[base + kt * 64];
    }

    float best[4][4];
    int btile[4][4];
#pragma unroll
    for (int s = 0; s < 4; ++s)
#pragma unroll
        for (int r = 0; r < 4; ++r) { best[s][r] = -1e30f; btile[s][r] = 0; }

    // pair-B accumulators (loop-carried from tile it-1)
    f32x4 zz = (f32x4){0.f, 0.f, 0.f, 0.f};
    f32x4 pb0_2 = zz, pb1_2 = zz, pb0_3 = zz, pb1_3 = zz;

    const int NT = NEMBED / (16 * NQ);   // 128 tiles per slice
    for (int it = 0; it < NT; ++it) {
        // ---- pair A (sets 0,1) MFMAs on tile it ----
        f32x4 a0_0 = zz, a1_0 = zz, a0_1 = zz, a1_1 = zz;
#pragma unroll
        for (int kt = 0; kt < 4; ++kt) {
            a0_0 = __builtin_amdgcn_mfma_f32_16x16x32_f16(ahi[0][kt], bh[kt], a0_0, 0, 0, 0);
            a1_0 = __builtin_amdgcn_mfma_f32_16x16x32_f16(ahi[0][kt], bl[kt], a1_0, 0, 0, 0);
            a1_0 = __builtin_amdgcn_mfma_f32_16x16x32_f16(alo[0][kt], bh[kt], a1_0, 0, 0, 0);
            a0_1 = __builtin_amdgcn_mfma_f32_16x16x32_f16(ahi[1][kt], bh[kt], a0_1, 0, 0, 0);
            a1_1 = __builtin_amdgcn_mfma_f32_16x16x32_f16(ahi[1][kt], bl[kt], a1_1, 0, 0, 0);
            a1_1 = __builtin_amdgcn_mfma_f32_16x16x32_f16(alo[1][kt], bh[kt], a1_1, 0, 0, 0);
        }
        // ---- combine pair B of tile it-1 (overlaps pair-A MFMAs above) ----
        if (it > 0) {
#pragma unroll
            for (int r = 0; r < 4; ++r) {
                float v2 = fmaf(pb1_2[r], SCALE_DN, pb0_2[r]);
                if (v2 > best[2][r]) { best[2][r] = v2; btile[2][r] = it - 1; }
                float v3 = fmaf(pb1_3[r], SCALE_DN, pb0_3[r]);
                if (v3 > best[3][r]) { best[3][r] = v3; btile[3][r] = it - 1; }
            }
        }
        // ---- pair B (sets 2,3) MFMAs on tile it; prefetch tile it+1 B after last use ----
        pb0_2 = zz; pb1_2 = zz; pb0_3 = zz; pb1_3 = zz;
        size_t nb = base + (size_t)(it + 1) * 256;
        bool have = (it + 1) < NT;
#pragma unroll
        for (int kt = 0; kt < 4; ++kt) {
            pb0_2 = __builtin_amdgcn_mfma_f32_16x16x32_f16(ahi[2][kt], bh[kt], pb0_2, 0, 0, 0);
            pb1_2 = __builtin_amdgcn_mfma_f32_16x16x32_f16(ahi[2][kt], bl[kt], pb1_2, 0, 0, 0);
            pb1_2 = __builtin_amdgcn_mfma_f32_16x16x32_f16(alo[2][kt], bh[kt], pb1_2, 0, 0, 0);
            pb0_3 = __builtin_amdgcn_mfma_f32_16x16x32_f16(ahi[3][kt], bh[kt], pb0_3, 0, 0, 0);
            pb1_3 = __builtin_amdgcn_mfma_f32_16x16x32_f16(ahi[3][kt], bl[kt], pb1_3, 0, 0, 0);
            pb1_3 = __builtin_amdgcn_mfma_f32_16x16x32_f16(alo[3][kt], bh[kt], pb1_3, 0, 0, 0);
            if (have) {   // WAR-safe: MFMAs above already read bh/bl at issue
                bh[kt] = cf[nb + kt * 64];
                bl[kt] = cv[nb + kt * 64];
            }
        }
        // ---- combine pair A of tile it (overlaps pair-B MFMAs / next pair-A) ----
#pragma unroll
        for (int r = 0; r < 4; ++r) {
            float v0 = fmaf(a1_0[r], SCALE_DN, a0_0[r]);
            if (v0 > best[0][r]) { best[0][r] = v0; btile[0][r] = it; }
            float v1 = fmaf(a1_1[r], SCALE_DN, a0_1[r]);
            if (v1 > best[1][r]) { best[1][r] = v1; btile[1][r] = it; }
        }
    }
    // tail: combine pair B of tile NT-1
#pragma unroll
    for (int r = 0; r < 4; ++r) {
        float v2 = fmaf(pb1_2[r], SCALE_DN, pb0_2[r]);
        if (v2 > best[2][r]) { best[2][r] = v2; btile[2][r] = NT - 1; }
        float v3 = fmaf(pb1_3[r], SCALE_DN, pb0_3[r]);
        if (v3 > best[3][r]) { best[3][r] = v3; btile[3][r] = NT - 1; }
    }

#pragma unroll
    for (int s = 0; s < 4; ++s)
#pragma unroll
        for (int r = 0; r < 4; ++r) {
            int row = w * 64 + s * 16 + 4 * lg + r;
            redv[row][lr] = best[s][r];
            redi[row][lr] = q * (NEMBED / NQ) + btile[s][r] * 16 + lr;
        }
    __syncthreads();
    {
        float bv = redv[t][0]; int bi = redi[t][0];
#pragma unroll
        for (int c = 1; c < 16; ++c) {
            float v = redv[t][c]; int ii = redi[t][c];
            if (v > bv || (v == bv && ii < bi)) { bv = v; bi = ii; }
        }
        pv[(size_t)q * ROWS + row0 + t] = bv;
        pi[(size_t)q * ROWS + row0 + t] = bi;
    }
}

// ---------------- merge NQ slice-candidates per row -------------------------------------
__global__ __launch_bounds__(256) void merge_argmax(const float* __restrict__ pv,
                                                    const int* __restrict__ pi,
                                                    int* __restrict__ out) {
    int row = blockIdx.x * 256 + threadIdx.x;
    float bv = pv[row]; int bi = pi[row];
#pragma unroll
    for (int q = 1; q < NQ; ++q) {
        float v = pv[(size_t)q * ROWS + row];
        if (v > bv) { bv = v; bi = pi[(size_t)q * ROWS + row]; }   // ties -> lower q wins
    }
    out[row] = bi;
}

extern "C" void kernel_launch(void* const* d_in, const int* in_sizes, int n_in,
                              void* d_out, int out_size, void* d_ws, size_t ws_size,
                              hipStream_t stream) {
    const float* x    = (const float*)d_in[0];   // [32,256,512]
    const float* proj = (const float*)d_in[1];   // [512,128]
    const float* cb   = (const float*)d_in[2];   // [1,8192,128]
    const int*   rm   = (const int*)d_in[3];     // [257]
    int* out = (int*)d_out;                      // [32,256,4,1] int32

    char* wsb = (char*)d_ws;
    _Float16* Wth  = (_Float16*)(wsb + 0);           // 512 KB
    _Float16* Wtl  = (_Float16*)(wsb + 524288);      // 512 KB
    _Float16* chi  = (_Float16*)(wsb + 1048576);     // 2 MB (B-fragment order)
    _Float16* clo  = (_Float16*)(wsb + 3145728);     // 2 MB
    _Float16* fhi  = (_Float16*)(wsb + 5242880);     // 8 MB
    _Float16* flo  = (_Float16*)(wsb + 13631488);    // 8 MB
    float*    pv   = (float*)(wsb + 22020096);       // 512 KB
    int*      pi   = (int*)(wsb + 22544384);         // 512 KB (end ~23 MB)

    prep_kernel<<<640, 256, 0, stream>>>(cb, proj, rm, chi, clo, Wth, Wtl);
    fused_feat<<<dim3(128, 4), 256, 0, stream>>>(x, Wth, Wtl, fhi, flo);
    sim_argmax_part<<<dim3(ROWS / 256, NQ), 256, 0, stream>>>(fhi, flo, chi, clo, pv, pi);
    merge_argmax<<<ROWS / 256, 256, 0, stream>>>(pv, pi, out);
}